// Round 1
// baseline (12.200 us; speedup 1.0000x reference)
//
#include <hip/hip_runtime.h>

// GaussianEmbedding margin loss:
//   kl(b,w,±) = 0.5 * sum_e [ s1/s2 + (m2-m1)^2/s2 - 1 + log(s2) - log(s1) ]
//   loss = mean_b sum_w max(0, MARGIN - kl_pos + kl_neg)
//
// Kernel 1: one 64-lane wave per b. Each lane owns 2 consecutive elements
// (float2, coalesced 512B row reads). All gather loads issued up front to
// pay HBM latency once. 10 butterfly reductions -> hinge -> partial[b].
// Kernel 2: deterministic single-block reduction of 1024 partials, /B.

constexpr int E = 128;
constexpr int W = 5;
constexpr int NB = 1024;               // B
constexpr float MARGIN = 0.1f;
constexpr float LN2 = 0.69314718055994530942f;

__global__ __launch_bounds__(64) void gauss_emb_kl(
    const float* __restrict__ mu, const float* __restrict__ sigma,
    const int* __restrict__ target, const int* __restrict__ cpos,
    const int* __restrict__ cneg, float* __restrict__ partial)
{
    const int b = blockIdx.x;
    const int lane = threadIdx.x;      // 0..63, lane handles elems 2*lane, 2*lane+1

    const int t = target[b];           // target is [B,1]
    const float2 m1 = ((const float2*)(mu    + (size_t)t * E))[lane];
    const float2 s1 = ((const float2*)(sigma + (size_t)t * E))[lane];

    int idx[2 * W];
#pragma unroll
    for (int k = 0; k < W; ++k) idx[k]     = cpos[b * W + k];
#pragma unroll
    for (int k = 0; k < W; ++k) idx[W + k] = cneg[b * W + k];

    // Issue all gather loads before any compute (latency overlap).
    float2 m2[2 * W], s2[2 * W];
#pragma unroll
    for (int k = 0; k < 2 * W; ++k) {
        m2[k] = ((const float2*)(mu    + (size_t)idx[k] * E))[lane];
        s2[k] = ((const float2*)(sigma + (size_t)idx[k] * E))[lane];
    }

    const float l1x = __log2f(s1.x);
    const float l1y = __log2f(s1.y);

    float kl[2 * W];
#pragma unroll
    for (int k = 0; k < 2 * W; ++k) {
        const float dx = m2[k].x - m1.x;
        const float dy = m2[k].y - m1.y;
        const float cx = (s1.x + dx * dx) / s2[k].x + LN2 * (__log2f(s2[k].x) - l1x);
        const float cy = (s1.y + dy * dy) / s2[k].y + LN2 * (__log2f(s2[k].y) - l1y);
        kl[k] = cx + cy - 2.0f;        // per-lane contribution (2 elems), the "-1" x2
    }

    // Butterfly reduce each of the 10 KL sums across the wave.
#pragma unroll
    for (int k = 0; k < 2 * W; ++k) {
#pragma unroll
        for (int off = 32; off >= 1; off >>= 1)
            kl[k] += __shfl_xor(kl[k], off, 64);
    }

    if (lane == 0) {
        float h = 0.f;
#pragma unroll
        for (int w = 0; w < W; ++w)
            h += fmaxf(0.f, MARGIN - 0.5f * kl[w] + 0.5f * kl[W + w]);
        partial[b] = h;
    }
}

__global__ __launch_bounds__(256) void gauss_emb_reduce(
    const float* __restrict__ partial, float* __restrict__ out)
{
    __shared__ float wave_sums[4];
    float s = 0.f;
    for (int i = threadIdx.x; i < NB; i += 256) s += partial[i];
#pragma unroll
    for (int off = 32; off >= 1; off >>= 1)
        s += __shfl_xor(s, off, 64);
    const int wid = threadIdx.x >> 6;
    if ((threadIdx.x & 63) == 0) wave_sums[wid] = s;
    __syncthreads();
    if (threadIdx.x == 0) {
        const float tot = wave_sums[0] + wave_sums[1] + wave_sums[2] + wave_sums[3];
        out[0] = tot * (1.0f / (float)NB);
    }
}

extern "C" void kernel_launch(void* const* d_in, const int* in_sizes, int n_in,
                              void* d_out, int out_size, void* d_ws, size_t ws_size,
                              hipStream_t stream)
{
    const float* mu     = (const float*)d_in[0];
    const float* sigma  = (const float*)d_in[1];
    const int*   target = (const int*)d_in[2];
    const int*   cpos   = (const int*)d_in[3];
    const int*   cneg   = (const int*)d_in[4];
    float* partial = (float*)d_ws;     // 1024 floats of scratch

    gauss_emb_kl<<<NB, 64, 0, stream>>>(mu, sigma, target, cpos, cneg, partial);
    gauss_emb_reduce<<<1, 256, 0, stream>>>(partial, (float*)d_out);
}